// Round 14
// baseline (622.052 us; speedup 1.0000x reference)
//
#include <hip/hip_runtime.h>
#include <cstddef>
#include <cstdint>

#define BATCH 32
#define CCH   512
#define OCH   1024
#define HW    3136
#define WDIM  56
#define NKT   16           // 512 / BK, BK=32

typedef __attribute__((ext_vector_type(8))) short short8v;  // 8 bf16
typedef __attribute__((ext_vector_type(4))) float f32x4;

// RNE round two fp32 to bf16, packed (x0 -> lo16, x1 -> hi16).
static __device__ __forceinline__ unsigned rne2(float x0, float x1) {
    unsigned u0 = __float_as_uint(x0), u1 = __float_as_uint(x1);
    u0 = u0 + 0x7fffu + ((u0 >> 16) & 1u);
    u1 = u1 + 0x7fffu + ((u1 >> 16) & 1u);
    return (u0 >> 16) | (u1 & 0xffff0000u);
}

// 4 slots of 16B per 64-B row; XOR swizzle (R10/R13-proven).
static __device__ __forceinline__ int physlot4(int s, int row) {
    return (s ^ (row & 3) ^ ((row >> 2) & 3)) & 3;
}

#define GLD_LDS16(gsrc, ldst) \
    __builtin_amdgcn_global_load_lds( \
        (const __attribute__((address_space(1))) void*)(gsrc), \
        (__attribute__((address_space(3))) void*)(ldst), 16, 0, 0)

#define MFMA16(a, bb, c) __builtin_amdgcn_mfma_f32_16x16x32_bf16((a), (bb), (c), 0, 0, 0)

// ---------------------------------------------------------------------------
// K0a: pre-convert weights (RNE bf16) into the LDS image (R10-proven).
// ---------------------------------------------------------------------------
__global__ __launch_bounds__(256) void preconv_w(
    const float* __restrict__ wp, unsigned char* __restrict__ wcvt)
{
    const int id = blockIdx.x * 256 + threadIdx.x;   // 16384 = 1024 o x 16 kt
    const int o = id >> 4, kt = id & 15;
    const float* p = wp + (size_t)o * CCH + kt * 32;
    unsigned char* dst = wcvt + (size_t)o * 1024 + kt * 64;
    float4 v[8];
#pragma unroll
    for (int r = 0; r < 8; ++r) v[r] = *(const float4*)(p + 4 * r);
#pragma unroll
    for (int oc = 0; oc < 4; ++oc) {
        uint4 w;
        w.x = rne2(v[2*oc].x,   v[2*oc].y);
        w.y = rne2(v[2*oc].z,   v[2*oc].w);
        w.z = rne2(v[2*oc+1].x, v[2*oc+1].y);
        w.w = rne2(v[2*oc+1].z, v[2*oc+1].w);
        *(uint4*)(dst + physlot4(oc, o) * 16) = w;
    }
}

// ---------------------------------------------------------------------------
// K0b: convert+transpose input to bin[b][kt][n] 64-B chunks, pre-swizzled
// with physlot4(sub, n) (R13-proven byte-exact LDS image).
// ---------------------------------------------------------------------------
__global__ __launch_bounds__(256) void conv_in(
    const float* __restrict__ in, unsigned char* __restrict__ bin)
{
    const int nt = blockIdx.x;      // 0..48 (64-n tiles)
    const int kt = blockIdx.y;      // 0..15
    const int b  = blockIdx.z;
    const int t  = threadIdx.x;
    __shared__ float sm[32 * 65];

    const int n0 = nt * 64;
    const int row = t >> 3;             // 0..31 (k within tile)
    const int c8  = (t & 7) * 8;        // 0..56
    const float* src = in + ((size_t)b * CCH + kt * 32 + row) * HW + n0 + c8;
    float4 v0 = *(const float4*)src;
    float4 v1 = *(const float4*)(src + 4);
    float* sr = sm + row * 65 + c8;
    sr[0] = v0.x; sr[1] = v0.y; sr[2] = v0.z; sr[3] = v0.w;
    sr[4] = v1.x; sr[5] = v1.y; sr[6] = v1.z; sr[7] = v1.w;
    __syncthreads();

    const int n = t >> 2, sub = t & 3;  // n 0..63, k-octet sub
    const int k0 = sub * 8;
    uint4 w;
    w.x = rne2(sm[(k0 + 0) * 65 + n], sm[(k0 + 1) * 65 + n]);
    w.y = rne2(sm[(k0 + 2) * 65 + n], sm[(k0 + 3) * 65 + n]);
    w.z = rne2(sm[(k0 + 4) * 65 + n], sm[(k0 + 5) * 65 + n]);
    w.w = rne2(sm[(k0 + 6) * 65 + n], sm[(k0 + 7) * 65 + n]);
    *(uint4*)(bin + (((size_t)b * 16 + kt) * HW + n0 + n) * 64 +
              physlot4(sub, n) * 16) = w;
}

// ---------------------------------------------------------------------------
// K1: m97-replica GEMM (R13 loop verbatim). NEW epilogue: accumulator is
// transposed through the 32 KB LDS (2 passes of 64 o-rows, col rotated by
// 4*row -> 2-way conflicts only) and stored as contiguous float4 rows:
// full 128-B lines per store -> no L2 read-for-ownership (R13's FETCH
// showed ~300 MB of RFO from scattered 4-B stores).
// ---------------------------------------------------------------------------
__global__ __launch_bounds__(256, 4) void gemm_m97(
    const unsigned char* __restrict__ wc,  // wcvt image
    const unsigned char* __restrict__ bin, // input image
    const float* __restrict__ bp,          // [1024]
    float* __restrict__ gate,              // d_out
    float* __restrict__ scan)              // ws scan region
{
    const int ot = blockIdx.x;   // 0..7  o-tile (fastest -> pins XCD)
    const int bx = blockIdx.y;   // 0..24 n-tile (last is half)
    const int b  = blockIdx.z;
    const int t  = threadIdx.x;
    const int lane = t & 63;
    const int wid  = t >> 6;           // 0..3
    const int wm = wid >> 1;           // o-strip of 64
    const int wn = wid & 1;            // n-strip of 64
    const int l15 = lane & 15, lko = lane >> 4;

    __shared__ __align__(16) unsigned char lds[32768];
    unsigned char* const A0 = lds;             // 8 KB (128 rows x 64 B)
    unsigned char* const A1 = lds + 8192;
    unsigned char* const B0 = lds + 16384;
    unsigned char* const B1 = lds + 24576;

    const int o0 = ot * 128;
    const int n0 = bx * 128;

    // staging sources (per-lane global, wave-uniform linear LDS dest)
    const unsigned char* aSrc = wc + (size_t)(o0 + (t >> 2)) * 1024 + (t & 3) * 16;
    const unsigned char* bSrc = bin + ((size_t)b * 16 * HW + n0) * 64 + t * 16;

    auto stage = [&](int kt, unsigned char* Ab, unsigned char* Bb) {
#pragma unroll
        for (int j = 0; j < 2; ++j)
            GLD_LDS16(aSrc + kt * 64 + (size_t)(j * 64) * 1024,
                      Ab + j * 4096 + wid * 1024);
#pragma unroll
        for (int j = 0; j < 2; ++j)
            GLD_LDS16(bSrc + (size_t)kt * (HW * 64) + j * 4096,
                      Bb + j * 4096 + wid * 1024);
    };

    f32x4 acc[4][4] = {};

    auto body = [&](int kt, unsigned char* Ac, unsigned char* Bc,
                    unsigned char* An, unsigned char* Bn) {
        // ---- stage next tile (DMA flies under the MFMAs) ----
        if (kt + 1 < NKT) stage(kt + 1, An, Bn);

        // ---- fragments ----
        short8v af[4], bf[4];
#pragma unroll
        for (int fi = 0; fi < 4; ++fi) {
            const int r = wm * 64 + fi * 16 + l15;
            af[fi] = *(const short8v*)(Ac + r * 64 + physlot4(lko, r) * 16);
        }
#pragma unroll
        for (int g = 0; g < 4; ++g) {
            const int n = wn * 64 + g * 16 + l15;
            bf[g] = *(const short8v*)(Bc + n * 64 + physlot4(lko, n) * 16);
        }

        __builtin_amdgcn_s_setprio(1);
#pragma unroll
        for (int fi = 0; fi < 4; ++fi)
#pragma unroll
            for (int g = 0; g < 4; ++g)
                acc[fi][g] = MFMA16(af[fi], bf[g], acc[fi][g]);
        __builtin_amdgcn_s_setprio(0);

        // ---- full drain + barrier (m97 structure; hidden by 4 blocks/CU) ----
        asm volatile("s_waitcnt vmcnt(0) lgkmcnt(0)" ::: "memory");
        __builtin_amdgcn_s_barrier();
        asm volatile("" ::: "memory");
    };

    // ---- prologue: tile 0 -> buf0 ----
    stage(0, A0, B0);
    asm volatile("s_waitcnt vmcnt(0)" ::: "memory");
    __builtin_amdgcn_s_barrier();
    asm volatile("" ::: "memory");

#pragma unroll 1
    for (int kt2 = 0; kt2 < NKT; kt2 += 2) {
        body(kt2,     A0, B0, A1, B1);
        body(kt2 + 1, A1, B1, A0, B0);
    }

    // ---- epilogue: LDS-transposed, fully-coalesced float4 stores ----
    float* dstb = (ot < 4) ? gate : scan;
    const int c0 = o0 & (CCH - 1);
    float* tile = (float*)lds;   // 64 rows x 128 cols fp32 = 32 KB

#pragma unroll 1
    for (int p = 0; p < 2; ++p) {
        __syncthreads();   // previous pass reads (or K-loop) done
        if (wm == p) {
#pragma unroll
            for (int f = 0; f < 4; ++f)
#pragma unroll
                for (int rg = 0; rg < 4; ++rg) {
                    const int row = f * 16 + lko * 4 + rg;
                    const float bias = bp[o0 + p * 64 + row];
#pragma unroll
                    for (int g = 0; g < 4; ++g) {
                        const int col = wn * 64 + g * 16 + l15;
                        tile[row * 128 + ((col + 4 * row) & 127)] =
                            acc[f][g][rg] + bias;
                    }
                }
        }
        __syncthreads();
        // cooperative store: 64 rows x 128 floats, 256 thr x 8 float4
#pragma unroll
        for (int j = 0; j < 8; ++j) {
            const int idx = t + j * 256;        // float4 index
            const int row = idx >> 5;           // 32 float4 per row
            const int c4  = idx & 31;
            const int n   = n0 + c4 * 4;
            if (n < HW) {
                f32x4 v = *(const f32x4*)&tile[row * 128 + ((c4 * 4 + 4 * row) & 127)];
                *(f32x4*)(dstb + ((size_t)b * CCH + c0 + p * 64 + row) * HW + n) = v;
            }
        }
    }
}

// ---------------------------------------------------------------------------
// Fallback GEMM (R0-proven fp32) if ws lacks room for bin.
// ---------------------------------------------------------------------------
__global__ __launch_bounds__(256) void gemm_proj(
    const float* __restrict__ in, const float* __restrict__ wp,
    const float* __restrict__ bp, float* __restrict__ gate,
    float* __restrict__ scan)
{
    const int bx = blockIdx.x, by = blockIdx.y, b = blockIdx.z;
    const int t = threadIdx.x;
    __shared__ float As[16][128];
    __shared__ float Bs[16][64];
    const float* Ab = wp + (size_t)(by * 128) * CCH;
    const float* Bb = in + (size_t)b * CCH * HW + bx * 64;
    float acc[8][4];
#pragma unroll
    for (int i = 0; i < 8; i++)
#pragma unroll
        for (int j = 0; j < 4; j++) acc[i][j] = 0.f;
    const int a_row = t >> 1, a_c = (t & 1) * 8;
    const int b_row = t >> 4, b_n = (t & 15) * 4;
    const int ty = t >> 4, tx = t & 15;
    for (int k0 = 0; k0 < CCH; k0 += 16) {
        float4 av0 = *(const float4*)(Ab + (size_t)a_row * CCH + k0 + a_c);
        float4 av1 = *(const float4*)(Ab + (size_t)a_row * CCH + k0 + a_c + 4);
        float4 bv  = *(const float4*)(Bb + (size_t)(k0 + b_row) * HW + b_n);
        __syncthreads();
        As[a_c + 0][a_row] = av0.x; As[a_c + 1][a_row] = av0.y;
        As[a_c + 2][a_row] = av0.z; As[a_c + 3][a_row] = av0.w;
        As[a_c + 4][a_row] = av1.x; As[a_c + 5][a_row] = av1.y;
        As[a_c + 6][a_row] = av1.z; As[a_c + 7][a_row] = av1.w;
        *(float4*)&Bs[b_row][b_n] = bv;
        __syncthreads();
#pragma unroll
        for (int kk = 0; kk < 16; kk++) {
            float4 a0 = *(const float4*)&As[kk][ty * 8];
            float4 a1 = *(const float4*)&As[kk][ty * 8 + 4];
            float4 bb = *(const float4*)&Bs[kk][tx * 4];
            float av[8] = {a0.x, a0.y, a0.z, a0.w, a1.x, a1.y, a1.z, a1.w};
            float bw[4] = {bb.x, bb.y, bb.z, bb.w};
#pragma unroll
            for (int i = 0; i < 8; i++)
#pragma unroll
                for (int j = 0; j < 4; j++)
                    acc[i][j] = fmaf(av[i], bw[j], acc[i][j]);
        }
    }
    const int n0 = bx * 64 + tx * 4;
#pragma unroll
    for (int i = 0; i < 8; i++) {
        const int o = by * 128 + ty * 8 + i;
        const float bias = bp[o];
        float4 v;
        v.x = acc[i][0] + bias; v.y = acc[i][1] + bias;
        v.z = acc[i][2] + bias; v.w = acc[i][3] + bias;
        float* dst;
        if (o < CCH) dst = gate + ((size_t)b * CCH + o) * HW + n0;
        else         dst = scan + ((size_t)b * CCH + (o - CCH)) * HW + n0;
        *(float4*)dst = v;
    }
}

// ---------------------------------------------------------------------------
// K2: per-(b,c) 2D discounted scan + fused epilogue (R0-proven).
// ---------------------------------------------------------------------------
__global__ __launch_bounds__(64) void scan_fuse(
    const float* __restrict__ in,
    const float* __restrict__ scanb,
    const float* __restrict__ disc,
    const float* __restrict__ gamma,
    float* gate_out)
{
    const int idx = blockIdx.x;
    const int c = idx & (CCH - 1);
    const size_t base = (size_t)idx * HW;
    const float d = disc[c];
    const float g = gamma[0];
    const int lane = threadIdx.x;

    __shared__ float L[WDIM * 57];

    if (lane < WDIM) {
        const int w = lane;
        float acc = 0.f;
#pragma unroll 4
        for (int h = 0; h < WDIM; h++) {
            acc = fmaf(d, acc, scanb[base + h * WDIM + w]);
            L[h * 57 + w] = acc;
        }
    }
    __syncthreads();
    if (lane < WDIM) {
        const int h = lane;
        float acc = 0.f;
#pragma unroll 4
        for (int w = 0; w < WDIM; w++) {
            acc = fmaf(d, acc, L[h * 57 + w]);
            L[h * 57 + w] = acc;
        }
    }
    __syncthreads();
    if (lane < WDIM) {
        const int w = lane;
#pragma unroll 4
        for (int h = 0; h < WDIM; h++) {
            const size_t off = base + h * WDIM + w;
            const float xc = L[h * 57 + w];
            const float sg = 1.f / (1.f + __expf(-xc));
            const float val = fmaf(g * gate_out[off], sg, in[off]);
            gate_out[off] = val;
        }
    }
}

extern "C" void kernel_launch(void* const* d_in, const int* in_sizes, int n_in,
                              void* d_out, int out_size, void* d_ws, size_t ws_size,
                              hipStream_t stream) {
    const float* in = (const float*)d_in[0];
    const float* wp = (const float*)d_in[1];
    const float* bp = (const float*)d_in[2];
    const float* dc = (const float*)d_in[3];
    const float* gm = (const float*)d_in[4];
    float* out = (float*)d_out;

    const size_t scan_bytes = (size_t)BATCH * CCH * HW * 4;    // 205.5 MB
    const size_t wcvt_bytes = (size_t)OCH * CCH * 2;           // 1 MB
    const size_t bin_bytes  = (size_t)BATCH * 16 * HW * 64;    // 102.8 MB
    const bool pre = ws_size >= scan_bytes + wcvt_bytes + bin_bytes;

    unsigned char* wcvt = (unsigned char*)d_ws;
    unsigned char* bin  = (unsigned char*)d_ws + wcvt_bytes;
    float* scanp = (float*)((unsigned char*)d_ws +
                            (pre ? wcvt_bytes + bin_bytes : 0));

    if (pre) {
        preconv_w<<<64, 256, 0, stream>>>(wp, wcvt);
        conv_in<<<dim3(49, 16, BATCH), 256, 0, stream>>>(in, bin);
        gemm_m97<<<dim3(8, 25, BATCH), 256, 0, stream>>>(wcvt, bin, bp, out, scanp);
    } else {
        gemm_proj<<<dim3(HW / 64, OCH / 128, BATCH), 256, 0, stream>>>(
            in, wp, bp, out, scanp);
    }

    scan_fuse<<<BATCH * CCH, 64, 0, stream>>>(in, scanp, dc, gm, out);
}

// Round 15
// 515.984 us; speedup vs baseline: 1.2056x; 1.2056x over previous
//
#include <hip/hip_runtime.h>
#include <cstddef>
#include <cstdint>

#define BATCH 32
#define CCH   512
#define OCH   1024
#define HW    3136
#define WDIM  56
#define NKT   16           // 512 / BK, BK=32

typedef __attribute__((ext_vector_type(8))) short short8v;  // 8 bf16
typedef __attribute__((ext_vector_type(4))) float f32x4;

// RNE round two fp32 to bf16, packed (x0 -> lo16, x1 -> hi16).
static __device__ __forceinline__ unsigned rne2(float x0, float x1) {
    unsigned u0 = __float_as_uint(x0), u1 = __float_as_uint(x1);
    u0 = u0 + 0x7fffu + ((u0 >> 16) & 1u);
    u1 = u1 + 0x7fffu + ((u1 >> 16) & 1u);
    return (u0 >> 16) | (u1 & 0xffff0000u);
}

// 4 slots of 16B per 64-B row; XOR swizzle (R10/R13-proven).
static __device__ __forceinline__ int physlot4(int s, int row) {
    return (s ^ (row & 3) ^ ((row >> 2) & 3)) & 3;
}

#define GLD_LDS16(gsrc, ldst) \
    __builtin_amdgcn_global_load_lds( \
        (const __attribute__((address_space(1))) void*)(gsrc), \
        (__attribute__((address_space(3))) void*)(ldst), 16, 0, 0)

#define MFMA16(a, bb, c) __builtin_amdgcn_mfma_f32_16x16x32_bf16((a), (bb), (c), 0, 0, 0)

// ---------------------------------------------------------------------------
// K0a: pre-convert weights (RNE bf16) into the LDS image (R10-proven).
// ---------------------------------------------------------------------------
__global__ __launch_bounds__(256) void preconv_w(
    const float* __restrict__ wp, unsigned char* __restrict__ wcvt)
{
    const int id = blockIdx.x * 256 + threadIdx.x;   // 16384 = 1024 o x 16 kt
    const int o = id >> 4, kt = id & 15;
    const float* p = wp + (size_t)o * CCH + kt * 32;
    unsigned char* dst = wcvt + (size_t)o * 1024 + kt * 64;
    float4 v[8];
#pragma unroll
    for (int r = 0; r < 8; ++r) v[r] = *(const float4*)(p + 4 * r);
#pragma unroll
    for (int oc = 0; oc < 4; ++oc) {
        uint4 w;
        w.x = rne2(v[2*oc].x,   v[2*oc].y);
        w.y = rne2(v[2*oc].z,   v[2*oc].w);
        w.z = rne2(v[2*oc+1].x, v[2*oc+1].y);
        w.w = rne2(v[2*oc+1].z, v[2*oc+1].w);
        *(uint4*)(dst + physlot4(oc, o) * 16) = w;
    }
}

// ---------------------------------------------------------------------------
// K0b: convert+transpose input to bin[b][kt][n] 64-B chunks, pre-swizzled
// with physlot4(sub, n) (R13-proven byte-exact LDS image).
// ---------------------------------------------------------------------------
__global__ __launch_bounds__(256) void conv_in(
    const float* __restrict__ in, unsigned char* __restrict__ bin)
{
    const int nt = blockIdx.x;      // 0..48 (64-n tiles)
    const int kt = blockIdx.y;      // 0..15
    const int b  = blockIdx.z;
    const int t  = threadIdx.x;
    __shared__ float sm[32 * 65];

    const int n0 = nt * 64;
    const int row = t >> 3;             // 0..31 (k within tile)
    const int c8  = (t & 7) * 8;        // 0..56
    const float* src = in + ((size_t)b * CCH + kt * 32 + row) * HW + n0 + c8;
    float4 v0 = *(const float4*)src;
    float4 v1 = *(const float4*)(src + 4);
    float* sr = sm + row * 65 + c8;
    sr[0] = v0.x; sr[1] = v0.y; sr[2] = v0.z; sr[3] = v0.w;
    sr[4] = v1.x; sr[5] = v1.y; sr[6] = v1.z; sr[7] = v1.w;
    __syncthreads();

    const int n = t >> 2, sub = t & 3;  // n 0..63, k-octet sub
    const int k0 = sub * 8;
    uint4 w;
    w.x = rne2(sm[(k0 + 0) * 65 + n], sm[(k0 + 1) * 65 + n]);
    w.y = rne2(sm[(k0 + 2) * 65 + n], sm[(k0 + 3) * 65 + n]);
    w.z = rne2(sm[(k0 + 4) * 65 + n], sm[(k0 + 5) * 65 + n]);
    w.w = rne2(sm[(k0 + 6) * 65 + n], sm[(k0 + 7) * 65 + n]);
    *(uint4*)(bin + (((size_t)b * 16 + kt) * HW + n0 + n) * 64 +
              physlot4(sub, n) * 16) = w;
}

// ---------------------------------------------------------------------------
// K1: m97-replica GEMM (R13 loop + epilogue verbatim). ONLY change vs R13:
// block->work mapping. Flat 6400-block grid; xcd = id&7 so the 8 ot-blocks
// sharing one 128-KB bin slice are dispatch-adjacent ON THE SAME XCD (R13's
// ot-fastest grid put them on 8 different XCDs -> bin fetched ~4x from HBM).
// Per-XCD L2 working set: ~16 bin slices (2 MB) + wcvt (1 MB) < 4 MB.
// ---------------------------------------------------------------------------
__global__ __launch_bounds__(256, 4) void gemm_m97(
    const unsigned char* __restrict__ wc,  // wcvt image
    const unsigned char* __restrict__ bin, // input image
    const float* __restrict__ bp,          // [1024]
    float* __restrict__ gate,              // d_out
    float* __restrict__ scan)              // ws scan region
{
    // ---- XCD-grouped decode: same-(bx,b) ot-blocks share an XCD ----
    const int id  = blockIdx.x;        // 0..6399
    const int xcd = id & 7;
    const int m   = id >> 3;
    const int ot  = m & 7;             // o-tile 0..7
    const int j   = xcd + 8 * (m >> 3);   // 0..799
    const int bx  = j % 25;            // n-tile
    const int b   = j / 25;            // batch

    const int t  = threadIdx.x;
    const int lane = t & 63;
    const int wid  = t >> 6;           // 0..3
    const int wm = wid >> 1;           // o-strip of 64
    const int wn = wid & 1;            // n-strip of 64
    const int l15 = lane & 15, lko = lane >> 4;

    __shared__ __align__(16) unsigned char lds[32768];
    unsigned char* const A0 = lds;             // 8 KB (128 rows x 64 B)
    unsigned char* const A1 = lds + 8192;
    unsigned char* const B0 = lds + 16384;
    unsigned char* const B1 = lds + 24576;

    const int o0 = ot * 128;
    const int n0 = bx * 128;

    // staging sources (per-lane global, wave-uniform linear LDS dest)
    const unsigned char* aSrc = wc + (size_t)(o0 + (t >> 2)) * 1024 + (t & 3) * 16;
    const unsigned char* bSrc = bin + ((size_t)b * 16 * HW + n0) * 64 + t * 16;

    auto stage = [&](int kt, unsigned char* Ab, unsigned char* Bb) {
#pragma unroll
        for (int jj = 0; jj < 2; ++jj)
            GLD_LDS16(aSrc + kt * 64 + (size_t)(jj * 64) * 1024,
                      Ab + jj * 4096 + wid * 1024);
#pragma unroll
        for (int jj = 0; jj < 2; ++jj)
            GLD_LDS16(bSrc + (size_t)kt * (HW * 64) + jj * 4096,
                      Bb + jj * 4096 + wid * 1024);
    };

    f32x4 acc[4][4] = {};

    auto body = [&](int kt, unsigned char* Ac, unsigned char* Bc,
                    unsigned char* An, unsigned char* Bn) {
        // ---- stage next tile (DMA flies under the MFMAs) ----
        if (kt + 1 < NKT) stage(kt + 1, An, Bn);

        // ---- fragments ----
        short8v af[4], bf[4];
#pragma unroll
        for (int fi = 0; fi < 4; ++fi) {
            const int r = wm * 64 + fi * 16 + l15;
            af[fi] = *(const short8v*)(Ac + r * 64 + physlot4(lko, r) * 16);
        }
#pragma unroll
        for (int g = 0; g < 4; ++g) {
            const int n = wn * 64 + g * 16 + l15;
            bf[g] = *(const short8v*)(Bc + n * 64 + physlot4(lko, n) * 16);
        }

        __builtin_amdgcn_s_setprio(1);
#pragma unroll
        for (int fi = 0; fi < 4; ++fi)
#pragma unroll
            for (int g = 0; g < 4; ++g)
                acc[fi][g] = MFMA16(af[fi], bf[g], acc[fi][g]);
        __builtin_amdgcn_s_setprio(0);

        // ---- full drain + barrier (m97 structure; hidden by 4 blocks/CU) ----
        asm volatile("s_waitcnt vmcnt(0) lgkmcnt(0)" ::: "memory");
        __builtin_amdgcn_s_barrier();
        asm volatile("" ::: "memory");
    };

    // ---- prologue: tile 0 -> buf0 ----
    stage(0, A0, B0);
    asm volatile("s_waitcnt vmcnt(0)" ::: "memory");
    __builtin_amdgcn_s_barrier();
    asm volatile("" ::: "memory");

#pragma unroll 1
    for (int kt2 = 0; kt2 < NKT; kt2 += 2) {
        body(kt2,     A0, B0, A1, B1);
        body(kt2 + 1, A1, B1, A0, B0);
    }

    // ---- epilogue: bias + store (R13-proven) ----
    float* dstb = (ot < 4) ? gate : scan;
    const int c0 = o0 & (CCH - 1);
#pragma unroll
    for (int f = 0; f < 4; ++f) {
        const int rowb = wm * 64 + f * 16 + lko * 4;
#pragma unroll
        for (int rg = 0; rg < 4; ++rg) {
            const float bias = bp[o0 + rowb + rg];
            float* drow = dstb + ((size_t)b * CCH + c0 + rowb + rg) * HW;
#pragma unroll
            for (int g = 0; g < 4; ++g) {
                const int n = n0 + wn * 64 + g * 16 + l15;
                if (n < HW) drow[n] = acc[f][g][rg] + bias;
            }
        }
    }
}

// ---------------------------------------------------------------------------
// Fallback GEMM (R0-proven fp32) if ws lacks room for bin.
// ---------------------------------------------------------------------------
__global__ __launch_bounds__(256) void gemm_proj(
    const float* __restrict__ in, const float* __restrict__ wp,
    const float* __restrict__ bp, float* __restrict__ gate,
    float* __restrict__ scan)
{
    const int bx = blockIdx.x, by = blockIdx.y, b = blockIdx.z;
    const int t = threadIdx.x;
    __shared__ float As[16][128];
    __shared__ float Bs[16][64];
    const float* Ab = wp + (size_t)(by * 128) * CCH;
    const float* Bb = in + (size_t)b * CCH * HW + bx * 64;
    float acc[8][4];
#pragma unroll
    for (int i = 0; i < 8; i++)
#pragma unroll
        for (int j = 0; j < 4; j++) acc[i][j] = 0.f;
    const int a_row = t >> 1, a_c = (t & 1) * 8;
    const int b_row = t >> 4, b_n = (t & 15) * 4;
    const int ty = t >> 4, tx = t & 15;
    for (int k0 = 0; k0 < CCH; k0 += 16) {
        float4 av0 = *(const float4*)(Ab + (size_t)a_row * CCH + k0 + a_c);
        float4 av1 = *(const float4*)(Ab + (size_t)a_row * CCH + k0 + a_c + 4);
        float4 bv  = *(const float4*)(Bb + (size_t)(k0 + b_row) * HW + b_n);
        __syncthreads();
        As[a_c + 0][a_row] = av0.x; As[a_c + 1][a_row] = av0.y;
        As[a_c + 2][a_row] = av0.z; As[a_c + 3][a_row] = av0.w;
        As[a_c + 4][a_row] = av1.x; As[a_c + 5][a_row] = av1.y;
        As[a_c + 6][a_row] = av1.z; As[a_c + 7][a_row] = av1.w;
        *(float4*)&Bs[b_row][b_n] = bv;
        __syncthreads();
#pragma unroll
        for (int kk = 0; kk < 16; kk++) {
            float4 a0 = *(const float4*)&As[kk][ty * 8];
            float4 a1 = *(const float4*)&As[kk][ty * 8 + 4];
            float4 bb = *(const float4*)&Bs[kk][tx * 4];
            float av[8] = {a0.x, a0.y, a0.z, a0.w, a1.x, a1.y, a1.z, a1.w};
            float bw[4] = {bb.x, bb.y, bb.z, bb.w};
#pragma unroll
            for (int i = 0; i < 8; i++)
#pragma unroll
                for (int j = 0; j < 4; j++)
                    acc[i][j] = fmaf(av[i], bw[j], acc[i][j]);
        }
    }
    const int n0 = bx * 64 + tx * 4;
#pragma unroll
    for (int i = 0; i < 8; i++) {
        const int o = by * 128 + ty * 8 + i;
        const float bias = bp[o];
        float4 v;
        v.x = acc[i][0] + bias; v.y = acc[i][1] + bias;
        v.z = acc[i][2] + bias; v.w = acc[i][3] + bias;
        float* dst;
        if (o < CCH) dst = gate + ((size_t)b * CCH + o) * HW + n0;
        else         dst = scan + ((size_t)b * CCH + (o - CCH)) * HW + n0;
        *(float4*)dst = v;
    }
}

// ---------------------------------------------------------------------------
// K2: per-(b,c) 2D discounted scan + fused epilogue (R0-proven).
// ---------------------------------------------------------------------------
__global__ __launch_bounds__(64) void scan_fuse(
    const float* __restrict__ in,
    const float* __restrict__ scanb,
    const float* __restrict__ disc,
    const float* __restrict__ gamma,
    float* gate_out)
{
    const int idx = blockIdx.x;
    const int c = idx & (CCH - 1);
    const size_t base = (size_t)idx * HW;
    const float d = disc[c];
    const float g = gamma[0];
    const int lane = threadIdx.x;

    __shared__ float L[WDIM * 57];

    if (lane < WDIM) {
        const int w = lane;
        float acc = 0.f;
#pragma unroll 4
        for (int h = 0; h < WDIM; h++) {
            acc = fmaf(d, acc, scanb[base + h * WDIM + w]);
            L[h * 57 + w] = acc;
        }
    }
    __syncthreads();
    if (lane < WDIM) {
        const int h = lane;
        float acc = 0.f;
#pragma unroll 4
        for (int w = 0; w < WDIM; w++) {
            acc = fmaf(d, acc, L[h * 57 + w]);
            L[h * 57 + w] = acc;
        }
    }
    __syncthreads();
    if (lane < WDIM) {
        const int w = lane;
#pragma unroll 4
        for (int h = 0; h < WDIM; h++) {
            const size_t off = base + h * WDIM + w;
            const float xc = L[h * 57 + w];
            const float sg = 1.f / (1.f + __expf(-xc));
            const float val = fmaf(g * gate_out[off], sg, in[off]);
            gate_out[off] = val;
        }
    }
}

extern "C" void kernel_launch(void* const* d_in, const int* in_sizes, int n_in,
                              void* d_out, int out_size, void* d_ws, size_t ws_size,
                              hipStream_t stream) {
    const float* in = (const float*)d_in[0];
    const float* wp = (const float*)d_in[1];
    const float* bp = (const float*)d_in[2];
    const float* dc = (const float*)d_in[3];
    const float* gm = (const float*)d_in[4];
    float* out = (float*)d_out;

    const size_t scan_bytes = (size_t)BATCH * CCH * HW * 4;    // 205.5 MB
    const size_t wcvt_bytes = (size_t)OCH * CCH * 2;           // 1 MB
    const size_t bin_bytes  = (size_t)BATCH * 16 * HW * 64;    // 102.8 MB
    const bool pre = ws_size >= scan_bytes + wcvt_bytes + bin_bytes;

    unsigned char* wcvt = (unsigned char*)d_ws;
    unsigned char* bin  = (unsigned char*)d_ws + wcvt_bytes;
    float* scanp = (float*)((unsigned char*)d_ws +
                            (pre ? wcvt_bytes + bin_bytes : 0));

    if (pre) {
        preconv_w<<<64, 256, 0, stream>>>(wp, wcvt);
        conv_in<<<dim3(49, 16, BATCH), 256, 0, stream>>>(in, bin);
        gemm_m97<<<6400, 256, 0, stream>>>(wcvt, bin, bp, out, scanp);
    } else {
        gemm_proj<<<dim3(HW / 64, OCH / 128, BATCH), 256, 0, stream>>>(
            in, wp, bp, out, scanp);
    }

    scan_fuse<<<BATCH * CCH, 64, 0, stream>>>(in, scanp, dc, gm, out);
}